// Round 14
// baseline (48.645 us; speedup 1.0000x reference)
//
#include <hip/hip_runtime.h>

#define N     384
#define BSZ   192
#define NM1   383
#define D     1024
#define DELTA 0.1f
#define NT    24                    // 16-row panels / tiles per dim
#define NTILES (NT * (NT + 1) / 2)  // 300 upper-tri tiles
#define PANEL 16384                 // halfs per panel: 16 rows * 1024
#define NSW   (N * 2)               // sweep blocks: 2 per row

typedef __attribute__((ext_vector_type(8))) short bf16x8;
typedef __attribute__((ext_vector_type(4))) float f32x4;

__device__ __forceinline__ const float* feat_row(const float* feats, int i) {
    // features laid out [192][2][1024]; logical row i of the [384,1024] concat
    int b = (i < BSZ) ? i : (i - BSZ);
    int s = (i < BSZ) ? 0 : 1;
    return feats + (size_t)(b * 2 + s) * D;
}

__device__ __forceinline__ unsigned short f2bf(float x) {  // RNE f32->bf16
    unsigned u = __builtin_bit_cast(unsigned, x);
    u = (u + 0x7FFFu + ((u >> 16) & 1u)) >> 16;
    return (unsigned short)u;
}
__device__ __forceinline__ float bf2f(unsigned short h) {
    unsigned u = ((unsigned)h) << 16;
    return __builtin_bit_cast(float, u);
}

// Fragment-major tiled index: (row, k) -> [row/16][k/8][row%16][k%8]
__device__ __forceinline__ size_t tidx(int row, int k) {
    return (size_t)(row >> 4) * PANEL + (size_t)(k >> 3) * 128
         + (size_t)(row & 15) * 8 + (k & 7);
}

// f32 -> (H, L) bf16 split, fragment-major + |f|^2. One row per block.
__global__ __launch_bounds__(256) void k_cvt(const float* __restrict__ feats,
                                             unsigned short* __restrict__ Ht,
                                             unsigned short* __restrict__ Lt,
                                             float* __restrict__ sq,
                                             unsigned* __restrict__ counter) {
    const int i = blockIdx.x, tid = threadIdx.x;
    const int lane = tid & 63, wv = tid >> 6;
    if (i == 0 && tid == 0) *counter = 0u;
    __shared__ float redp[4];

    const float4 v = ((const float4*)feat_row(feats, i))[tid];   // 256*4 = 1024
    float p = 0.f;
    p = fmaf(v.x, v.x, p); p = fmaf(v.y, v.y, p);
    p = fmaf(v.z, v.z, p); p = fmaf(v.w, v.w, p);
    ushort4 h, l;
    h.x = f2bf(v.x); l.x = f2bf(v.x - bf2f(h.x));
    h.y = f2bf(v.y); l.y = f2bf(v.y - bf2f(h.y));
    h.z = f2bf(v.z); l.z = f2bf(v.z - bf2f(h.z));
    h.w = f2bf(v.w); l.w = f2bf(v.w - bf2f(h.w));
    const size_t o = tidx(i, 4 * tid);      // (4*tid)%8 in {0,4}: 8B-aligned
    *(ushort4*)(Ht + o) = h;
    *(ushort4*)(Lt + o) = l;

#pragma unroll
    for (int off = 32; off; off >>= 1) p += __shfl_xor(p, off);
    if (lane == 0) redp[wv] = p;
    __syncthreads();
    if (tid == 0) sq[i] = redp[0] + redp[1] + redp[2] + redp[3];
}

// Gram via MFMA on fragment-major H/L (unchanged; measured ~2.9us in R11).
__global__ __launch_bounds__(256) void k_gram(const unsigned short* __restrict__ Ht,
                                              const unsigned short* __restrict__ Lt,
                                              const float* __restrict__ sq,
                                              float* __restrict__ z) {
    int t = blockIdx.x, bi = 0;
    while (t >= NT - bi) { t -= NT - bi; ++bi; }
    const int bj = bi + t;
    const bool diag = (bi == bj);

    const int tid = threadIdx.x;
    const int lane = tid & 63, wv = tid >> 6;

    const size_t aBase = (size_t)bi * PANEL + (size_t)(wv * 32 + (lane >> 4)) * 128
                       + (size_t)(lane & 15) * 8;
    const size_t bBase = (size_t)bj * PANEL + (size_t)(wv * 32 + (lane >> 4)) * 128
                       + (size_t)(lane & 15) * 8;

    f32x4 aHH = {0.f,0.f,0.f,0.f}, aHL = {0.f,0.f,0.f,0.f}, aLH = {0.f,0.f,0.f,0.f};
#pragma unroll
    for (int s = 0; s < 8; ++s) {
        bf16x8 aH = *(const bf16x8*)(Ht + aBase + s * 512);
        bf16x8 aL = *(const bf16x8*)(Lt + aBase + s * 512);
        bf16x8 bH = *(const bf16x8*)(Ht + bBase + s * 512);
        bf16x8 bL = *(const bf16x8*)(Lt + bBase + s * 512);
        aHH = __builtin_amdgcn_mfma_f32_16x16x32_bf16(aH, bH, aHH, 0, 0, 0);
        aHL = __builtin_amdgcn_mfma_f32_16x16x32_bf16(aH, bL, aHL, 0, 0, 0);
        aLH = __builtin_amdgcn_mfma_f32_16x16x32_bf16(aL, bH, aLH, 0, 0, 0);
    }
    __shared__ f32x4 red[4][64];
    red[wv][lane] = aHH + aHL + aLH;
    __syncthreads();
    const int ls = tid & 63, r = tid >> 6;
    float g = red[0][ls][r] + red[1][ls][r] + red[2][ls][r] + red[3][ls][r];
    // C/D layout (verified): col = lane&15, row = (lane>>4)*4 + reg
    const int jj = bj * 16 + (ls & 15);
    const int ii = bi * 16 + ((ls >> 4) << 2) + r;
    if (ii != jj && (!diag || ii < jj)) {
        float sd = fmaxf(sq[ii] + sq[jj] - 2.f * g, 0.f);
        float v  = sqrtf(sd);
        z[ii * NM1 + (jj < ii ? jj : jj - 1)] = v;
        z[jj * NM1 + (ii < jj ? ii : ii - 1)] = v;
    }
}

// Per-row counting sort by y_abs -> zsort (float2: z, rank*DELTA; slot 383 =
// (0,0) pad). Also computes the sparse same-y correction and subtracts the
// analytic pad compensation sum_j (zj-rj)^2 (the sweep's k=383 pad pairs).
__global__ __launch_bounds__(256) void k_prep(const float* __restrict__ z,
                                              const int* __restrict__ labels,
                                              float2* __restrict__ zsort,
                                              float* __restrict__ partial) {
    const int i = blockIdx.x, tid = threadIdx.x;
    __shared__ float zbuf[NM1];
    __shared__ unsigned char yrow[NM1];
    __shared__ int cnt[64], startv[64], cur[64];
    __shared__ float rankd[64];
    __shared__ float2 zr[N];
    __shared__ unsigned grs[N];

    if (tid < 64) cnt[tid] = 0;
    for (int k = tid; k < NM1; k += 256) zbuf[k] = z[i * NM1 + k];
    __syncthreads();
    const int li = labels[(i < BSZ) ? i : (i - BSZ)];
    for (int k = tid; k < NM1; k += 256) {
        int col = k + (k >= i ? 1 : 0);
        int ya  = abs(li - labels[(col < BSZ) ? col : (col - BSZ)]);
        yrow[k] = (unsigned char)ya;
        atomicAdd(&cnt[ya], 1);
    }
    __syncthreads();
    if (tid == 0) {
        int c = 0, r = 0;
        for (int v = 0; v < 64; ++v) {
            startv[v] = c;
            rankd[v]  = (float)r * DELTA;
            if (cnt[v] > 0) ++r;
            c += cnt[v];
        }
    }
    __syncthreads();
    if (tid < 64) cur[tid] = startv[tid];
    __syncthreads();
    for (int k = tid; k < NM1; k += 256) {
        int ya  = yrow[k];
        int pos = atomicAdd(&cur[ya], 1);
        zr[pos]  = make_float2(zbuf[k], rankd[ya]);
        grs[pos] = (unsigned)startv[ya] | ((unsigned)(startv[ya] + cnt[ya]) << 9);
    }
    if (tid == 0) zr[NM1] = make_float2(0.f, 0.f);
    __syncthreads();

    // write sorted row (incl. pad slot) to global for the sweep kernel
    for (int k = tid; k < N; k += 256) zsort[i * N + k] = zr[k];

    // correction over same-y pairs minus pad compensation
    float cs = 0.f;
    for (int kk = tid; kk < NM1; kk += 256) {
        const float    zj = zr[kk].x;
        const unsigned g  = grs[kk];
        const int lo = g & 0x1FF;
        const int hi = (g >> 9) & 0x1FF;
        for (int k = lo; k < hi; ++k) {
            float a = fabsf(zr[k].x - zj);
            cs += a * __builtin_amdgcn_rcpf(1.f + __expf(DELTA - a)) - a * a;
        }
    }
    for (int j = tid; j < NM1; j += 256) {
        float2 q = zr[j];
        float d = q.x - q.y;          // pad pair (k=383): (|0-z|-|0-r|)^2
        cs = fmaf(-d, d, cs);
    }

#pragma unroll
    for (int off = 32; off; off >>= 1) cs += __shfl_xor(cs, off);
    __shared__ float part[4];
    if ((tid & 63) == 0) part[tid >> 6] = cs;
    __syncthreads();
    if (tid == 0) partial[i * 3] = part[0] + part[1] + part[2] + part[3];
}

// All-pairs sweep, no LDS in the hot loop: each thread holds 6 k-slots in
// registers (64*6=384 covers all k incl pad); each wave sweeps a j-subrange
// (8 subranges of 48 per row, 2 blocks/row). 768 blocks -> ~12 waves/CU.
__global__ __launch_bounds__(256) void k_sweep(const float2* __restrict__ zsort,
                                               float* __restrict__ partial,
                                               unsigned* __restrict__ counter,
                                               float* __restrict__ out) {
    const int b = blockIdx.x, tid = threadIdx.x;
    const int i = b >> 1, h = b & 1;
    const int lane = tid & 63, wv = tid >> 6;
    __shared__ float part[4];
    __shared__ int lastFlag;

    const float2* zrow = zsort + i * N;
    float zk[6], rk[6];
#pragma unroll
    for (int s = 0; s < 6; ++s) {
        float2 q = zrow[lane + 64 * s];   // coalesced; slot 383 = (0,0) pad
        zk[s] = q.x; rk[s] = q.y;
    }

    const int u  = h * 4 + wv;            // subrange 0..7
    const int j0 = u * 48;
    const int j1 = (j0 + 48 < NM1) ? j0 + 48 : NM1;

    float a0 = 0.f, a1 = 0.f, a2 = 0.f, a3 = 0.f, a4 = 0.f, a5 = 0.f;
    for (int j = j0; j < j1; ++j) {
        const float2 q = zrow[j];         // wave-uniform: one L1 line/request
        float t0 = fabsf(zk[0] - q.x) - fabsf(rk[0] - q.y); a0 = fmaf(t0, t0, a0);
        float t1 = fabsf(zk[1] - q.x) - fabsf(rk[1] - q.y); a1 = fmaf(t1, t1, a1);
        float t2 = fabsf(zk[2] - q.x) - fabsf(rk[2] - q.y); a2 = fmaf(t2, t2, a2);
        float t3 = fabsf(zk[3] - q.x) - fabsf(rk[3] - q.y); a3 = fmaf(t3, t3, a3);
        float t4 = fabsf(zk[4] - q.x) - fabsf(rk[4] - q.y); a4 = fmaf(t4, t4, a4);
        float t5 = fabsf(zk[5] - q.x) - fabsf(rk[5] - q.y); a5 = fmaf(t5, t5, a5);
    }

    float sum = ((a0 + a1) + (a2 + a3)) + (a4 + a5);
#pragma unroll
    for (int off = 32; off; off >>= 1) sum += __shfl_xor(sum, off);
    if (lane == 0) part[wv] = sum;
    __syncthreads();
    if (tid == 0) {
        partial[i * 3 + 1 + h] = part[0] + part[1] + part[2] + part[3];
        __threadfence();
        unsigned old = atomicAdd(counter, 1u);
        lastFlag = (old == NSW - 1);
    }
    __syncthreads();

    if (lastFlag) {
        // atomic reads bypass any stale per-XCD L2 lines
        double s = 0.0;
        for (int t2 = tid; t2 < N * 3; t2 += 256)
            s += (double)atomicAdd(&partial[t2], 0.f);
#pragma unroll
        for (int off = 32; off; off >>= 1) s += __shfl_xor(s, off);
        __shared__ double dp[4];
        if ((tid & 63) == 0) dp[tid >> 6] = s;
        __syncthreads();
        if (tid == 0) {
            const double M = (double)N * (double)NM1 * (double)NM1;
            out[0] = (float)((dp[0] + dp[1] + dp[2] + dp[3]) / M);
        }
    }
}

extern "C" void kernel_launch(void* const* d_in, const int* in_sizes, int n_in,
                              void* d_out, int out_size, void* d_ws, size_t ws_size,
                              hipStream_t stream) {
    const float* feats  = (const float*)d_in[0];
    const int*   labels = (const int*)d_in[1];
    float*       out    = (float*)d_out;

    // ws layout (~3.5 MB total):
    char* ws = (char*)d_ws;
    float*          sq      = (float*)ws;                          // 1536 B
    unsigned*       counter = (unsigned*)(ws + 2048);              // 4 B
    float*          partial = (float*)(ws + 4096);                 // 4608 B
    unsigned short* Ht      = (unsigned short*)(ws + 16384);       // 768 KiB
    unsigned short* Lt      = (unsigned short*)(ws + 16384 + 786432);          // 768 KiB
    float*          z       = (float*)(ws + 16384 + 2 * 786432);   // 588 KiB
    float2*         zsort   = (float2*)(ws + 16384 + 2 * 786432 + 602112);     // 1.2 MiB

    k_cvt  <<<N, 256, 0, stream>>>(feats, Ht, Lt, sq, counter);
    k_gram <<<NTILES, 256, 0, stream>>>(Ht, Lt, sq, z);
    k_prep <<<N, 256, 0, stream>>>(z, labels, zsort, partial);
    k_sweep<<<NSW, 256, 0, stream>>>(zsort, partial, counter, out);
}

// Round 15
// 31.552 us; speedup vs baseline: 1.5417x; 1.5417x over previous
//
#include <hip/hip_runtime.h>

#define N     384
#define BSZ   192
#define NM1   383
#define D     1024
#define DELTA 0.1f
#define NT    24                    // 16-row panels / tiles per dim
#define NTILES (NT * (NT + 1) / 2)  // 300 upper-tri tiles
#define PANEL 16384                 // halfs per panel: 16 rows * 1024

typedef __attribute__((ext_vector_type(8))) short bf16x8;
typedef __attribute__((ext_vector_type(4))) float f32x4;

__device__ __forceinline__ const float* feat_row(const float* feats, int i) {
    // features laid out [192][2][1024]; logical row i of the [384,1024] concat
    int b = (i < BSZ) ? i : (i - BSZ);
    int s = (i < BSZ) ? 0 : 1;
    return feats + (size_t)(b * 2 + s) * D;
}

__device__ __forceinline__ unsigned short f2bf(float x) {  // RNE f32->bf16
    unsigned u = __builtin_bit_cast(unsigned, x);
    u = (u + 0x7FFFu + ((u >> 16) & 1u)) >> 16;
    return (unsigned short)u;
}
__device__ __forceinline__ float bf2f(unsigned short h) {
    unsigned u = ((unsigned)h) << 16;
    return __builtin_bit_cast(float, u);
}

// Fragment-major tiled index: (row, k) -> [row/16][k/8][row%16][k%8]
__device__ __forceinline__ size_t tidx(int row, int k) {
    return (size_t)(row >> 4) * PANEL + (size_t)(k >> 3) * 128
         + (size_t)(row & 15) * 8 + (k & 7);
}

// f32 -> (H, L) bf16 split, fragment-major + |f|^2. One row per block
// (384 blocks: R9's 96-block version left 160 CUs idle -> 8.5us).
__global__ __launch_bounds__(256) void k_cvt(const float* __restrict__ feats,
                                             unsigned short* __restrict__ Ht,
                                             unsigned short* __restrict__ Lt,
                                             float* __restrict__ sq) {
    const int i = blockIdx.x, tid = threadIdx.x;
    const int lane = tid & 63, wv = tid >> 6;
    __shared__ float redp[4];

    const float4 v = ((const float4*)feat_row(feats, i))[tid];   // 256*4 = 1024
    float p = 0.f;
    p = fmaf(v.x, v.x, p); p = fmaf(v.y, v.y, p);
    p = fmaf(v.z, v.z, p); p = fmaf(v.w, v.w, p);
    ushort4 h, l;
    h.x = f2bf(v.x); l.x = f2bf(v.x - bf2f(h.x));
    h.y = f2bf(v.y); l.y = f2bf(v.y - bf2f(h.y));
    h.z = f2bf(v.z); l.z = f2bf(v.z - bf2f(h.z));
    h.w = f2bf(v.w); l.w = f2bf(v.w - bf2f(h.w));
    const size_t o = tidx(i, 4 * tid);      // (4*tid)%8 in {0,4}: 8B-aligned
    *(ushort4*)(Ht + o) = h;
    *(ushort4*)(Lt + o) = l;

#pragma unroll
    for (int off = 32; off; off >>= 1) p += __shfl_xor(p, off);
    if (lane == 0) redp[wv] = p;
    __syncthreads();
    if (tid == 0) sq[i] = redp[0] + redp[1] + redp[2] + redp[3];
}

// Gram via MFMA on fragment-major H/L (unchanged; measured ~2.9us in R11).
__global__ __launch_bounds__(256) void k_gram(const unsigned short* __restrict__ Ht,
                                              const unsigned short* __restrict__ Lt,
                                              const float* __restrict__ sq,
                                              float* __restrict__ z) {
    int t = blockIdx.x, bi = 0;
    while (t >= NT - bi) { t -= NT - bi; ++bi; }
    const int bj = bi + t;
    const bool diag = (bi == bj);

    const int tid = threadIdx.x;
    const int lane = tid & 63, wv = tid >> 6;

    const size_t aBase = (size_t)bi * PANEL + (size_t)(wv * 32 + (lane >> 4)) * 128
                       + (size_t)(lane & 15) * 8;
    const size_t bBase = (size_t)bj * PANEL + (size_t)(wv * 32 + (lane >> 4)) * 128
                       + (size_t)(lane & 15) * 8;

    f32x4 aHH = {0.f,0.f,0.f,0.f}, aHL = {0.f,0.f,0.f,0.f}, aLH = {0.f,0.f,0.f,0.f};
#pragma unroll
    for (int s = 0; s < 8; ++s) {
        bf16x8 aH = *(const bf16x8*)(Ht + aBase + s * 512);
        bf16x8 aL = *(const bf16x8*)(Lt + aBase + s * 512);
        bf16x8 bH = *(const bf16x8*)(Ht + bBase + s * 512);
        bf16x8 bL = *(const bf16x8*)(Lt + bBase + s * 512);
        aHH = __builtin_amdgcn_mfma_f32_16x16x32_bf16(aH, bH, aHH, 0, 0, 0);
        aHL = __builtin_amdgcn_mfma_f32_16x16x32_bf16(aH, bL, aHL, 0, 0, 0);
        aLH = __builtin_amdgcn_mfma_f32_16x16x32_bf16(aL, bH, aLH, 0, 0, 0);
    }
    __shared__ f32x4 red[4][64];
    red[wv][lane] = aHH + aHL + aLH;
    __syncthreads();
    const int ls = tid & 63, r = tid >> 6;
    float g = red[0][ls][r] + red[1][ls][r] + red[2][ls][r] + red[3][ls][r];
    // C/D layout (verified): col = lane&15, row = (lane>>4)*4 + reg
    const int jj = bj * 16 + (ls & 15);
    const int ii = bi * 16 + ((ls >> 4) << 2) + r;
    if (ii != jj && (!diag || ii < jj)) {
        float sd = fmaxf(sq[ii] + sq[jj] - 2.f * g, 0.f);
        float v  = sqrtf(sd);
        z[ii * NM1 + (jj < ii ? jj : jj - 1)] = v;
        z[jj * NM1 + (ii < jj ? ii : ii - 1)] = v;
    }
}

// One block per row, 512 threads. R9 structure with two fixes:
//  - parallel shfl_up prefix scan replaces the tid==0 serial 64-bin loop
//  - per-row partial write only; finalize moved to k_fin (kills the
//    384-deep same-address atomic tail measured ~5us)
__global__ __launch_bounds__(512) void k_main(const float* __restrict__ z,
                                              const int* __restrict__ labels,
                                              float* __restrict__ partial) {
    const int i = blockIdx.x, tid = threadIdx.x;
    __shared__ float zbuf[NM1];
    __shared__ unsigned char yrow[NM1];
    __shared__ int cnt[64], startv[64], cur[64];
    __shared__ float rankd[64];
    __shared__ float2 zr[N];      // sorted (z, rank*DELTA); slot 383 = pad
    __shared__ unsigned grs[N];   // lo | hi<<9 per sorted slot

    if (tid < 64) cnt[tid] = 0;
    for (int k = tid; k < NM1; k += 512) zbuf[k] = z[i * NM1 + k];
    __syncthreads();
    const int li = labels[(i < BSZ) ? i : (i - BSZ)];
    for (int k = tid; k < NM1; k += 512) {
        int col = k + (k >= i ? 1 : 0);
        int ya  = abs(li - labels[(col < BSZ) ? col : (col - BSZ)]);
        yrow[k] = (unsigned char)ya;
        atomicAdd(&cnt[ya], 1);
    }
    __syncthreads();
    if (tid < 64) {                    // wave-0 parallel exclusive scans
        const int c  = cnt[tid];
        const int nz = (c > 0) ? 1 : 0;
        int sc = c, sn = nz;
#pragma unroll
        for (int d = 1; d < 64; d <<= 1) {
            int tc = __shfl_up(sc, d);
            int tn = __shfl_up(sn, d);
            if (tid >= d) { sc += tc; sn += tn; }
        }
        startv[tid] = sc - c;          // exclusive prefix of counts
        cur[tid]    = sc - c;
        rankd[tid]  = (float)(sn - nz) * DELTA;   // dense rank * DELTA
    }
    __syncthreads();
    for (int k = tid; k < NM1; k += 512) {
        int ya  = yrow[k];
        int pos = atomicAdd(&cur[ya], 1);
        zr[pos]  = make_float2(zbuf[k], rankd[ya]);
        grs[pos] = (unsigned)startv[ya] | ((unsigned)(startv[ya] + cnt[ya]) << 9);
    }
    if (tid == 0) zr[NM1] = make_float2(0.f, 0.f);
    __syncthreads();

    // all-pairs term: (|zk-zj| - |rk-rj|)^2, one k-slot per thread
    const bool  kv  = (tid < NM1);
    const int   k0  = kv ? tid : NM1;      // pad slot for inactive threads
    const float zk0 = zr[k0].x, rk0 = zr[k0].y;

    float s0 = 0.f;
#define PAIRQ(q) do { \
        float t0 = fabsf(zk0 - (q).x) - fabsf(rk0 - (q).y); s0 = fmaf(t0, t0, s0); \
    } while (0)
    int j = 0;
    for (; j + 8 <= NM1; j += 8) {
        float2 q0 = zr[j],   q1 = zr[j+1], q2 = zr[j+2], q3 = zr[j+3];
        float2 q4 = zr[j+4], q5 = zr[j+5], q6 = zr[j+6], q7 = zr[j+7];
        PAIRQ(q0); PAIRQ(q1); PAIRQ(q2); PAIRQ(q3);
        PAIRQ(q4); PAIRQ(q5); PAIRQ(q6); PAIRQ(q7);
    }
    for (; j < NM1; ++j) { float2 q = zr[j]; PAIRQ(q); }
#undef PAIRQ
    if (!kv) s0 = 0.f;

    // correction over same-y pairs: a*sigmoid(a-DELTA) - a^2 over [lo,hi)
    float cs = 0.f;
    if (kv) {
        const float    zj = zr[tid].x;
        const unsigned g  = grs[tid];
        const int lo = g & 0x1FF;
        const int hi = (g >> 9) & 0x1FF;
        for (int k = lo; k < hi; ++k) {
            float a = fabsf(zr[k].x - zj);
            cs += a * __builtin_amdgcn_rcpf(1.f + __expf(DELTA - a)) - a * a;
        }
    }

    float sum = s0 + cs;
#pragma unroll
    for (int off = 32; off; off >>= 1) sum += __shfl_xor(sum, off);
    __shared__ float part[8];
    if ((tid & 63) == 0) part[tid >> 6] = sum;
    __syncthreads();
    if (tid == 0) {
        float ps = 0.f;
#pragma unroll
        for (int w = 0; w < 8; ++w) ps += part[w];
        partial[i] = ps;
    }
}

__global__ __launch_bounds__(512) void k_fin(const float* __restrict__ partial,
                                             float* __restrict__ out) {
    const int tid = threadIdx.x;
    double s = (tid < N) ? (double)partial[tid] : 0.0;
#pragma unroll
    for (int off = 32; off; off >>= 1) s += __shfl_xor(s, off);
    __shared__ double dp[8];
    if ((tid & 63) == 0) dp[tid >> 6] = s;
    __syncthreads();
    if (tid == 0) {
        double ds = 0.0;
#pragma unroll
        for (int w = 0; w < 8; ++w) ds += dp[w];
        const double M = (double)N * (double)NM1 * (double)NM1;
        out[0] = (float)(ds / M);
    }
}

extern "C" void kernel_launch(void* const* d_in, const int* in_sizes, int n_in,
                              void* d_out, int out_size, void* d_ws, size_t ws_size,
                              hipStream_t stream) {
    const float* feats  = (const float*)d_in[0];
    const int*   labels = (const int*)d_in[1];
    float*       out    = (float*)d_out;

    // ws layout (~2.2 MB total):
    char* ws = (char*)d_ws;
    float*          sq      = (float*)ws;                          // 1536 B
    float*          partial = (float*)(ws + 4096);                 // 1536 B
    unsigned short* Ht      = (unsigned short*)(ws + 16384);       // 768 KiB
    unsigned short* Lt      = (unsigned short*)(ws + 16384 + 786432);        // 768 KiB
    float*          z       = (float*)(ws + 16384 + 2 * 786432);   // 588 KiB

    k_cvt <<<N, 256, 0, stream>>>(feats, Ht, Lt, sq);
    k_gram<<<NTILES, 256, 0, stream>>>(Ht, Lt, sq, z);
    k_main<<<N, 512, 0, stream>>>(z, labels, partial);
    k_fin <<<1, 512, 0, stream>>>(partial, out);
}